// Round 15
// baseline (200.006 us; speedup 1.0000x reference)
//
#include <hip/hip_runtime.h>
#include <math.h>

#define F_DIM 128
#define D_LAT 64
#define H_DIM 128

typedef __attribute__((ext_vector_type(8))) short bf16x8;
typedef __attribute__((ext_vector_type(4))) float f32x4;
typedef __attribute__((ext_vector_type(2))) float f32x2;

__device__ __forceinline__ unsigned short f2bf(float f) {
    unsigned int u = __builtin_bit_cast(unsigned int, f);
    return (unsigned short)((u + 0x8000u) >> 16);
}

#define GLDS16(gaddr, laddr)                                                        \
    __builtin_amdgcn_global_load_lds(                                               \
        (const __attribute__((address_space(1))) void*)(gaddr),                     \
        (__attribute__((address_space(3))) void*)(laddr), 16, 0, 0)

// ---------------- encoder via MFMA (unchanged, verified R2-R14) ----------------
// mfma 16x16x32 layouts (m89-verified):
//   A: lane l, elem j -> A[l&15][(l>>4)*8 + j]
//   B: lane l, elem j -> B[(l>>4)*8 + j][l&15]
//   D: lane l, reg r  -> D[(l>>4)*4 + r][l&15]
__global__ __launch_bounds__(256) void enc_mfma_kernel(
    const float* __restrict__ x, const float* __restrict__ eps,
    const float* __restrict__ Wmu, const float* __restrict__ bmu,
    const float* __restrict__ Wlv, const float* __restrict__ blv,
    unsigned char* __restrict__ zb, float* __restrict__ accum, int nNodes)
{
    const int lane = threadIdx.x & 63;
    const int li   = lane & 15;
    const int gi   = lane >> 4;

    bf16x8 wf[8][4];
#pragma unroll
    for (int t = 0; t < 4; ++t)
#pragma unroll
        for (int s = 0; s < 4; ++s)
#pragma unroll
            for (int j = 0; j < 8; ++j) {
                const int k = s * 32 + gi * 8 + j;
                wf[t][s][j]     = (short)f2bf(Wmu[k * D_LAT + 16 * t + li]);
                wf[t + 4][s][j] = (short)f2bf(Wlv[k * D_LAT + 16 * t + li]);
            }
    float bmu4[4], blv4[4];
#pragma unroll
    for (int t = 0; t < 4; ++t) {
        bmu4[t] = bmu[16 * t + li];
        blv4[t] = blv[16 * t + li];
    }

    const int wid = (blockIdx.x * blockDim.x + threadIdx.x) >> 6;
    const int nw  = (gridDim.x * blockDim.x) >> 6;
    const int NB  = nNodes >> 4;

    float klacc = 0.f;
    for (int nb = wid; nb < NB; nb += nw) {
        const int nbase = nb << 4;
        const float* __restrict__ xrow = x + (size_t)(nbase + li) * F_DIM;

        bf16x8 af[4];
#pragma unroll
        for (int s = 0; s < 4; ++s) {
            const f32x4 v0 = *(const f32x4*)(xrow + s * 32 + gi * 8);
            const f32x4 v1 = *(const f32x4*)(xrow + s * 32 + gi * 8 + 4);
#pragma unroll
            for (int j = 0; j < 4; ++j) {
                af[s][j]     = (short)f2bf(v0[j]);
                af[s][j + 4] = (short)f2bf(v1[j]);
            }
        }

        f32x4 acc[8];
#pragma unroll
        for (int t = 0; t < 4; ++t) {
            acc[t]     = (f32x4){bmu4[t], bmu4[t], bmu4[t], bmu4[t]};
            acc[t + 4] = (f32x4){blv4[t], blv4[t], blv4[t], blv4[t]};
        }
#pragma unroll
        for (int t = 0; t < 8; ++t)
#pragma unroll
            for (int s = 0; s < 4; ++s)
                acc[t] = __builtin_amdgcn_mfma_f32_16x16x32_bf16(af[s], wf[t][s], acc[t], 0, 0, 0);

#pragma unroll
        for (int r = 0; r < 4; ++r) {
            const int row = nbase + gi * 4 + r;
#pragma unroll
            for (int t = 0; t < 4; ++t) {
                const float mu  = acc[t][r];
                const float lv  = acc[t + 4][r];
                const float e05 = __expf(0.5f * lv);
                klacc += mu * mu + e05 * e05 - 1.0f - lv;
                const float zv = fmaf(eps[(size_t)row * D_LAT + 16 * t + li], e05, mu);
                zb[(size_t)row * D_LAT + 16 * t + li] =
                    (unsigned char)(__builtin_amdgcn_cvt_pk_fp8_f32(zv, 0.f, 0u, false) & 0xffu);
            }
        }
    }
    for (int off = 32; off; off >>= 1) klacc += __shfl_xor(klacc, off);
    if (lane == 0) atomicAdd(&accum[1], 0.5f * klacc);
}

// ---------------- repack fp8 z -> fp4 (custom e2m1 index coding, verified R14) ----------------
__global__ __launch_bounds__(256) void repack_fp4_kernel(
    const unsigned char* __restrict__ zb, unsigned int* __restrict__ zb4, int n8)
{
    const int stride = gridDim.x * blockDim.x;
    for (int i = blockIdx.x * blockDim.x + threadIdx.x; i < n8; i += stride) {
        const unsigned long long q = *(const unsigned long long*)(zb + (size_t)i * 8);
        float f[8];
        f32x2 d;
        d = __builtin_amdgcn_cvt_pk_f32_fp8((unsigned int)q, false);  f[0] = d[0]; f[1] = d[1];
        d = __builtin_amdgcn_cvt_pk_f32_fp8((unsigned int)q, true);   f[2] = d[0]; f[3] = d[1];
        d = __builtin_amdgcn_cvt_pk_f32_fp8((unsigned int)(q >> 32), false); f[4] = d[0]; f[5] = d[1];
        d = __builtin_amdgcn_cvt_pk_f32_fp8((unsigned int)(q >> 32), true);  f[6] = d[0]; f[7] = d[1];
        unsigned int out = 0;
#pragma unroll
        for (int k = 0; k < 8; ++k) {
            const float a = fabsf(f[k]);
            // RNE thresholds for grid {0,0.5,1,1.5,2,3,4,6}
            unsigned int n = (a < 0.25f) ? 0u : (a < 0.75f) ? 1u : (a < 1.25f) ? 2u :
                             (a < 1.75f) ? 3u : (a < 2.5f)  ? 4u : (a < 3.5f)  ? 5u :
                             (a < 5.0f)  ? 6u : 7u;
            if (f[k] < 0.f) n |= 8u;
            out |= n << (4 * k);
        }
        zb4[i] = out;
    }
}

// ---------------- edge scorer: fp4 rows + 256B product LUT (exact e4m3) ----------------
// Product of two e2m1 values is exactly representable in e4m3 -> plut[(un<<4)|vn]
// gives the fp8 product byte; bit-identical to R14's cvt-chain (both exact-f32 + RNE).
// Ring: 2 idx + 2 glds = 4 vm-ops/iter; slot staged 2 iters ago -> vmcnt(4).
__global__ __launch_bounds__(256) void edge_mfma_kernel(
    const unsigned char* __restrict__ zb4,
    const int* __restrict__ eidx, const int* __restrict__ nidx,
    const float* __restrict__ W1, const float* __restrict__ b1,
    const float* __restrict__ W2, const float* __restrict__ b2,
    float* __restrict__ accum, int E)
{
    __shared__ unsigned char sh[4][2][2][1024];   // [wave][slot][u/v][32 rows * 32B] = 16KB
    __shared__ long w1s[8][2][64];                // W1 fp8 fragments, 8KB
    __shared__ float bw[2][H_DIM];                // b1, W2
    __shared__ unsigned char plut[256];           // fp4 x fp4 -> fp8 product LUT

    const int lane = threadIdx.x & 63;
    const int li   = lane & 15;
    const int gi   = lane >> 4;
    const int w    = threadIdx.x >> 6;

    if (threadIdx.x < H_DIM) {
        bw[0][threadIdx.x] = b1[threadIdx.x];
        bw[1][threadIdx.x] = W2[threadIdx.x];
    }
    {   // build product LUT: index = (un<<4)|vn, nibble = sign<<3 | magIdx
        const int i  = threadIdx.x;          // 256 threads, one entry each
        const int un = i >> 4, vn = i & 15;
        const int au = un & 7, av = vn & 7;
        const float mu = (au == 0) ? 0.f : (au == 1) ? 0.5f
                       : ((au & 1) ? 1.5f : 1.0f) * (float)(1 << ((au >> 1) - 1));
        const float mv = (av == 0) ? 0.f : (av == 1) ? 0.5f
                       : ((av & 1) ? 1.5f : 1.0f) * (float)(1 << ((av >> 1) - 1));
        float f = mu * mv;
        if ((un ^ vn) & 8) f = -f;
        plut[i] = (unsigned char)(__builtin_amdgcn_cvt_pk_fp8_f32(f, 0.f, 0u, false) & 0xffu);
    }
#pragma unroll
    for (int k = 0; k < 2; ++k) {
        const int t = 2 * w + k;
#pragma unroll
        for (int s = 0; s < 2; ++s) {
            float f[8];
#pragma unroll
            for (int j = 0; j < 8; ++j)
                f[j] = W1[(gi * 16 + s * 8 + j) * H_DIM + 16 * t + li];
            unsigned int r0 = __builtin_amdgcn_cvt_pk_fp8_f32(f[0], f[1], 0u, false);
            r0 = __builtin_amdgcn_cvt_pk_fp8_f32(f[2], f[3], r0, true);
            unsigned int r1 = __builtin_amdgcn_cvt_pk_fp8_f32(f[4], f[5], 0u, false);
            r1 = __builtin_amdgcn_cvt_pk_fp8_f32(f[6], f[7], r1, true);
            w1s[t][s][lane] = (long)(((unsigned long long)r1 << 32) | r0);
        }
    }
    __syncthreads();

    const float b2v = b2[0];

    const int wid = (blockIdx.x * blockDim.x + threadIdx.x) >> 6;
    const int nw  = (gridDim.x * blockDim.x) >> 6;
    const int NBpos = E >> 5;          // 31250 positive 32-pair blocks
    const int NBH   = NBpos << 1;      // 62500 total blocks

    float lp = 0.f;
    const int myPair = lane >> 1;      // 2 lanes per 32B row
    const int chunk  = (lane & 1) << 4;

    auto load_idx = [&](int hb, int& u, int& v) {
        const int h = (hb < NBH) ? hb : (NBH - 1);
        const int* __restrict__ ia = (h < NBpos) ? eidx : nidx;
        const int m = ((h < NBpos) ? h : h - NBpos) << 5;
        u = ia[m + myPair]; v = ia[E + m + myPair];
    };
    auto stage = [&](int slot, int u, int v) {
        GLDS16(zb4 + (size_t)u * 32 + chunk, &sh[w][slot][0][0]);
        GLDS16(zb4 + (size_t)v * 32 + chunk, &sh[w][slot][1][0]);
    };
    // 16 fp4 products via LUT -> two fp8 i64 MFMA A-fragments
    auto lut_prod = [&](unsigned long long qu, unsigned long long qv, long& pa0, long& pa1) {
        const unsigned long long M  = 0x0F0F0F0F0F0F0F0FULL;
        const unsigned long long idxe = ((qu & M) << 4) | (qv & M);           // even dims
        const unsigned long long idxo = (qu & ~M) | ((qv >> 4) & M);          // odd dims
        const unsigned int e0 = (unsigned int)idxe, e1 = (unsigned int)(idxe >> 32);
        const unsigned int o0 = (unsigned int)idxo, o1 = (unsigned int)(idxo >> 32);
        const unsigned int pe0 = plut[e0 & 255], pe1 = plut[(e0 >> 8) & 255];
        const unsigned int pe2 = plut[(e0 >> 16) & 255], pe3 = plut[e0 >> 24];
        const unsigned int po0 = plut[o0 & 255], po1 = plut[(o0 >> 8) & 255];
        const unsigned int po2 = plut[(o0 >> 16) & 255], po3 = plut[o0 >> 24];
        const unsigned int pe4 = plut[e1 & 255], pe5 = plut[(e1 >> 8) & 255];
        const unsigned int pe6 = plut[(e1 >> 16) & 255], pe7 = plut[e1 >> 24];
        const unsigned int po4 = plut[o1 & 255], po5 = plut[(o1 >> 8) & 255];
        const unsigned int po6 = plut[(o1 >> 16) & 255], po7 = plut[o1 >> 24];
        const unsigned int lo0 = pe0 | (po0 << 8) | (pe1 << 16) | (po1 << 24);
        const unsigned int hi0 = pe2 | (po2 << 8) | (pe3 << 16) | (po3 << 24);
        const unsigned int lo1 = pe4 | (po4 << 8) | (pe5 << 16) | (po5 << 24);
        const unsigned int hi1 = pe6 | (po6 << 8) | (pe7 << 16) | (po7 << 24);
        pa0 = (long)(((unsigned long long)hi0 << 32) | lo0);
        pa1 = (long)(((unsigned long long)hi1 << 32) | lo1);
    };

    // ---- prologue ----
    int iu, iv;
    load_idx(wid, iu, iv);
    stage(0, iu, iv);
    load_idx(wid + nw, iu, iv);
    stage(1, iu, iv);
    load_idx(wid + 2 * nw, iu, iv);

    int slot = 0;
    for (int hb = wid; hb < NBH; hb += nw, slot ^= 1) {
        asm volatile("s_waitcnt vmcnt(4)" ::: "memory");
        const unsigned char* ubuf = &sh[w][slot][0][0];
        const unsigned char* vbuf = &sh[w][slot][1][0];

        const unsigned long long qu0 = *(const unsigned long long*)(ubuf + li * 32 + gi * 8);
        const unsigned long long qv0 = *(const unsigned long long*)(vbuf + li * 32 + gi * 8);
        const unsigned long long qu1 = *(const unsigned long long*)(ubuf + (16 + li) * 32 + gi * 8);
        const unsigned long long qv1 = *(const unsigned long long*)(vbuf + (16 + li) * 32 + gi * 8);
        asm volatile("s_waitcnt lgkmcnt(0)" ::: "memory");

        int ju, jv;
        load_idx(hb + 3 * nw, ju, jv);   // 2 vm-ops
        stage(slot, iu, iv);             // 2 vm-ops
        iu = ju; iv = jv;

        const float sg = (hb < NBpos) ? 1.f : -1.f;
#pragma unroll
        for (int b = 0; b < 2; ++b) {
            long pa0, pa1;
            lut_prod(b ? qu1 : qu0, b ? qv1 : qv0, pa0, pa1);
            float t0 = 0.f, t1 = 0.f, t2 = 0.f, t3 = 0.f;
#pragma unroll
            for (int t = 0; t < 8; ++t) {
                const float bb = bw[0][16 * t + li];
                f32x4 acc = (f32x4){bb, bb, bb, bb};
                acc = __builtin_amdgcn_mfma_f32_16x16x32_fp8_fp8(pa0, w1s[t][0][lane], acc, 0, 0, 0);
                acc = __builtin_amdgcn_mfma_f32_16x16x32_fp8_fp8(pa1, w1s[t][1][lane], acc, 0, 0, 0);
                const float w2v = bw[1][16 * t + li];
                t0 += fmaxf(acc[0], 0.f) * w2v;
                t1 += fmaxf(acc[1], 0.f) * w2v;
                t2 += fmaxf(acc[2], 0.f) * w2v;
                t3 += fmaxf(acc[3], 0.f) * w2v;
            }
#pragma unroll
            for (int off = 1; off < 16; off <<= 1) {
                t0 += __shfl_xor(t0, off);
                t1 += __shfl_xor(t1, off);
                t2 += __shfl_xor(t2, off);
                t3 += __shfl_xor(t3, off);
            }
            const float l0 = sg * (t0 + b2v), l1 = sg * (t1 + b2v);
            const float l2 = sg * (t2 + b2v), l3 = sg * (t3 + b2v);
            lp += fminf(l0, 0.f) - __logf(1.f + __expf(-fabsf(l0)));
            lp += fminf(l1, 0.f) - __logf(1.f + __expf(-fabsf(l1)));
            lp += fminf(l2, 0.f) - __logf(1.f + __expf(-fabsf(l2)));
            lp += fminf(l3, 0.f) - __logf(1.f + __expf(-fabsf(l3)));
        }
    }

    for (int off = 32; off; off >>= 1) lp += __shfl_xor(lp, off);
    if (lane == 0) atomicAdd(&accum[0], lp * 0.0625f);
}

// ---------------- finalize ----------------
__global__ void fin_kernel(const float* __restrict__ accum, float* __restrict__ out,
                           int nNodes, int E)
{
    const float recon = accum[0] / (float)(2 * E);
    const float kl    = accum[1] / (float)nNodes;
    out[0] = kl - recon;
}

extern "C" void kernel_launch(void* const* d_in, const int* in_sizes, int n_in,
                              void* d_out, int out_size, void* d_ws, size_t ws_size,
                              hipStream_t stream)
{
    const float* x    = (const float*)d_in[0];
    const float* eps  = (const float*)d_in[1];
    const float* Wmu  = (const float*)d_in[2];
    const float* bmu  = (const float*)d_in[3];
    const float* Wlv  = (const float*)d_in[4];
    const float* blv  = (const float*)d_in[5];
    const float* W1   = (const float*)d_in[6];
    const float* b1   = (const float*)d_in[7];
    const float* W2   = (const float*)d_in[8];
    const float* b2   = (const float*)d_in[9];
    const int*   eidx = (const int*)d_in[10];
    const int*   nidx = (const int*)d_in[11];

    const int nNodes = in_sizes[1] / D_LAT;   // 100000
    const int E      = in_sizes[10] / 2;      // 1000000

    char* ws = (char*)d_ws;
    float*         accum = (float*)ws;                              // 256 B
    unsigned char* zb    = (unsigned char*)(ws + 256);              // 6.4 MB fp8
    unsigned char* zb4   = (unsigned char*)(ws + 6400512);          // 3.2 MB fp4

    hipMemsetAsync(accum, 0, 256, stream);
    enc_mfma_kernel<<<512, 256, 0, stream>>>(x, eps, Wmu, bmu, Wlv, blv, zb, accum, nNodes);
    repack_fp4_kernel<<<3125, 256, 0, stream>>>(zb, (unsigned int*)zb4, nNodes * 8);
    edge_mfma_kernel<<<1536, 256, 0, stream>>>(zb4, eidx, nidx, W1, b1, W2, b2, accum, E);
    fin_kernel<<<1, 1, 0, stream>>>(accum, (float*)d_out, nNodes, E);
}